// Round 4
// baseline (1095.557 us; speedup 1.0000x reference)
//
#include <hip/hip_runtime.h>
#include <cstdint>
#include <cstddef>
#include <math.h>

#define M_ROWS 16384
#define N_COLS 1000
#define N_PAD  1024
#define K_DIM  4096
#define NUM_TTA 64
#define KEPT 6
#define BATCH 256
#define CHUNK_MAX 16384
#define N_TILES 8          // N_PAD / 128

typedef __attribute__((ext_vector_type(8))) short short8;
typedef __attribute__((ext_vector_type(4))) float v4f;

#define GL_LDS16(g, l)                                                        \
    __builtin_amdgcn_global_load_lds(                                         \
        (const __attribute__((address_space(1))) unsigned int*)(g),           \
        (__attribute__((address_space(3))) unsigned int*)(l), 16, 0, 0)

// ---- exact round-to-nearest-even bf16 split: x = hi + lo (+ ~2^-18 rel) ----
__device__ __forceinline__ unsigned short bf_rn(float x) {
    unsigned int u = __float_as_uint(x);
    return (unsigned short)((u + 0x7fffu + ((u >> 16) & 1u)) >> 16);
}
__device__ __forceinline__ void split2(float x, unsigned short& h, unsigned short& l) {
    h = bf_rn(x);
    float hf = __uint_as_float(((unsigned int)h) << 16);
    l = bf_rn(x - hf);
}

// ---------------- W: transpose 4096x1000 -> [n][k] 1024x4096, split ----------------
__global__ __launch_bounds__(1024)
void split_w(const float* __restrict__ W, unsigned short* __restrict__ Wh,
             unsigned short* __restrict__ Wl)
{
    __shared__ float tile[32][33];
    const int k0 = blockIdx.x * 32, n0 = blockIdx.y * 32;
    const int tx = threadIdx.x, ty = threadIdx.y;
    const int n = n0 + tx, k = k0 + ty;
    tile[ty][tx] = (n < N_COLS) ? W[(size_t)k * N_COLS + n] : 0.f;
    __syncthreads();
    const float w = tile[tx][ty];           // = W[k0+tx][n0+ty]
    unsigned short h, l;
    split2(w, h, l);
    const size_t o = (size_t)(n0 + ty) * K_DIM + k0 + tx;
    Wh[o] = h; Wl[o] = l;
}

// ---------------- A: split fp32 chunk -> hi/lo bf16 (same layout) ----------------
__global__ __launch_bounds__(256)
void split_a(const float* __restrict__ x, unsigned short* __restrict__ Ah,
             unsigned short* __restrict__ Al, long long nelem)
{
    const long long i = ((long long)blockIdx.x * 256 + threadIdx.x) * 8;
    if (i >= nelem) return;
    const float4 v0 = *(const float4*)(x + i);
    const float4 v1 = *(const float4*)(x + i + 4);
    unsigned short h[8], l[8];
    split2(v0.x, h[0], l[0]); split2(v0.y, h[1], l[1]);
    split2(v0.z, h[2], l[2]); split2(v0.w, h[3], l[3]);
    split2(v1.x, h[4], l[4]); split2(v1.y, h[5], l[5]);
    split2(v1.z, h[6], l[6]); split2(v1.w, h[7], l[7]);
    short8 hv, lv;
#pragma unroll
    for (int j = 0; j < 8; ++j) { hv[j] = (short)h[j]; lv[j] = (short)l[j]; }
    *(short8*)(Ah + i) = hv;
    *(short8*)(Al + i) = lv;
}

// ------------- GEMM: logits = A @ Wt^T + b via bf16 split-2 MFMA -------------
// 128x128 block tile, 256 thr = 4 waves each 64x64, 16x16x32 MFMA, BK=32.
// LDS is FRAGMENT-MAJOR: each 16-row x 32-k MFMA fragment = 64 lane-ordered
// 16B slots, so ds_read_b128 is lane-linear (conflict-free). Staging permutes
// which global (row,kq) each thread fetches so global_load_lds's fixed t*16
// LDS destination lands each element in its fragment slot.
__global__ __launch_bounds__(256, 4)
void gemm_mfma(const unsigned short* __restrict__ Ah, const unsigned short* __restrict__ Al,
               const unsigned short* __restrict__ Bh, const unsigned short* __restrict__ Bl,
               const float* __restrict__ bias, float* __restrict__ logits,
               int m_tiles)
{
    __shared__ short sAh[128 * 32];
    __shared__ short sAl[128 * 32];
    __shared__ short sBh[128 * 32];
    __shared__ short sBl[128 * 32];

    const int t = threadIdx.x;
    const int lane = t & 63;
    const int wave = t >> 6;
    const int ml = lane & 15;          // m (or n) within 16-tile
    const int half = lane >> 4;        // 0..3 -> k-quarter of 32
    const int wm = (wave >> 1) * 64, wn = (wave & 1) * 64;
    const int wmf = wm >> 4, wnf = wn >> 4;   // fragment-group base

    // ---- XCD swizzle (m_tiles divisible by 8; N_TILES == 8) ----
    const int bid  = blockIdx.x;
    const int xcd  = bid & 7;
    const int slot = bid >> 3;
    const int mt   = xcd * (m_tiles >> 3) + (slot >> 3);
    const int nt   = slot & 7;
    const int n0 = nt * 128;
    const int m0 = mt * 128;

    v4f acc[4][4];
#pragma unroll
    for (int i = 0; i < 4; ++i)
#pragma unroll
        for (int j = 0; j < 4; ++j) acc[i][j] = (v4f){0.f, 0.f, 0.f, 0.f};

    // staging map (fragment-major): slot s = t (and t+256):
    //   frag f = s>>6, lane-in-frag L = s&63, row = f*16 + (L&15), kq = L>>4
    const int row1 = (t >> 6) * 16 + (t & 15);      // 0..63
    const int kb1  = ((t >> 4) & 3) * 16;           // byte offset in 64B k-chunk
    const char* pAh = (const char*)Ah + (size_t)(m0 + row1) * (K_DIM * 2) + kb1;
    const char* pAl = (const char*)Al + (size_t)(m0 + row1) * (K_DIM * 2) + kb1;
    const char* pBh = (const char*)Bh + (size_t)(n0 + row1) * (K_DIM * 2) + kb1;
    const char* pBl = (const char*)Bl + (size_t)(n0 + row1) * (K_DIM * 2) + kb1;
    short* lAh = sAh + t * 8;  short* lAl = sAl + t * 8;
    short* lBh = sBh + t * 8;  short* lBl = sBl + t * 8;
    const size_t rstep = (size_t)64 * K_DIM * 2;    // slot2 = slot1 + 64 rows

    for (int kb = 0; kb < K_DIM * 2; kb += 64) {    // 32 k-values = 64 bytes/step
        GL_LDS16(pAh + kb, lAh);  GL_LDS16(pAh + rstep + kb, lAh + 2048);
        GL_LDS16(pAl + kb, lAl);  GL_LDS16(pAl + rstep + kb, lAl + 2048);
        GL_LDS16(pBh + kb, lBh);  GL_LDS16(pBh + rstep + kb, lBh + 2048);
        GL_LDS16(pBl + kb, lBl);  GL_LDS16(pBl + rstep + kb, lBl + 2048);
        __syncthreads();

        short8 ah[4], al[4], bh[4], bl[4];
#pragma unroll
        for (int i = 0; i < 4; ++i) {
            // fragment (wmf+i), slot = lane  -> conflict-free lane-linear read
            ah[i] = *(const short8*)&sAh[(wmf + i) * 512 + lane * 8];
            al[i] = *(const short8*)&sAl[(wmf + i) * 512 + lane * 8];
            bh[i] = *(const short8*)&sBh[(wnf + i) * 512 + lane * 8];
            bl[i] = *(const short8*)&sBl[(wnf + i) * 512 + lane * 8];
        }
#pragma unroll
        for (int i = 0; i < 4; ++i)
#pragma unroll
            for (int j = 0; j < 4; ++j) {
                acc[i][j] = __builtin_amdgcn_mfma_f32_16x16x32_bf16(ah[i], bl[j], acc[i][j], 0, 0, 0);
                acc[i][j] = __builtin_amdgcn_mfma_f32_16x16x32_bf16(al[i], bh[j], acc[i][j], 0, 0, 0);
                acc[i][j] = __builtin_amdgcn_mfma_f32_16x16x32_bf16(ah[i], bh[j], acc[i][j], 0, 0, 0);
            }
        __syncthreads();
    }

    // epilogue: C/D layout col = lane&15, row = (lane>>4)*4 + reg  [m89/m91]
#pragma unroll
    for (int i = 0; i < 4; ++i) {
        const int rbase = m0 + wm + i * 16 + half * 4;
#pragma unroll
        for (int j = 0; j < 4; ++j) {
            const int col = n0 + wn + j * 16 + ml;
            if (col < N_COLS) {
                const float bv = bias[col];
#pragma unroll
                for (int r = 0; r < 4; ++r)
                    logits[(size_t)(rbase + r) * N_COLS + col] = acc[i][j][r] + bv;
            }
        }
    }
}

// ------ per-view softmax stats: one WAVE per row, shuffle-only, no LDS ------
__global__ __launch_bounds__(256)
void row_stats(const float* __restrict__ logits, double* __restrict__ ent,
               int* __restrict__ votes, int v_base)
{
    const int wave = threadIdx.x >> 6;
    const int lane = threadIdx.x & 63;
    const int row = blockIdx.x * 4 + wave;
    const float* rp = logits + (size_t)row * N_COLS;

    float v[16];
    float bv = -3.0e38f; int bi = 0;
#pragma unroll
    for (int j = 0; j < 16; ++j) {
        const int c = lane + j * 64;
        const float x = (c < N_COLS) ? rp[c] : -3.0e38f;
        v[j] = x;
        if (x > bv) { bv = x; bi = c; }   // strict >, c increasing: first index
    }
    // wave argmax (value desc, index asc on ties)
#pragma unroll
    for (int off = 32; off > 0; off >>= 1) {
        const float ov = __shfl_down(bv, off, 64);
        const int   oi = __shfl_down(bi, off, 64);
        if (ov > bv || (ov == bv && oi < bi)) { bv = ov; bi = oi; }
    }
    const float mx = __shfl(bv, 0, 64);
    const int amax = __shfl(bi, 0, 64);

    double S = 0.0, T = 0.0;
#pragma unroll
    for (int j = 0; j < 16; ++j) {
        const int c = lane + j * 64;
        if (c < N_COLS) {
            const float d = v[j] - mx;        // fp32 like reference softmax
            const double e = exp((double)d);  // f64 accumulation
            S += e; T += e * (double)d;
        }
    }
#pragma unroll
    for (int off = 32; off > 0; off >>= 1) {
        S += __shfl_down(S, off, 64);
        T += __shfl_down(T, off, 64);
    }
    if (lane == 0) {
        ent[v_base + row]   = log(S) - T / S;
        votes[v_base + row] = amax;
    }
}

// ------------- per-batch voting: stable sort by entropy, tie loop -------------
__global__ __launch_bounds__(64)
void vote_kernel(const double* __restrict__ ent, const int* __restrict__ votes,
                 float* __restrict__ out)
{
    __shared__ double e[NUM_TTA];
    __shared__ int    sv[NUM_TTA];
    __shared__ float  counts[N_COLS];

    const int b = blockIdx.x;
    const int t = threadIdx.x;

    e[t] = ent[b * NUM_TTA + t];
    const int myv = votes[b * NUM_TTA + t];
    for (int c = t; c < N_COLS; c += NUM_TTA) counts[c] = 0.f;
    __syncthreads();

    const double et = e[t];
    int rank = 0;
#pragma unroll
    for (int i = 0; i < NUM_TTA; ++i) {
        const double ei = e[i];
        rank += (ei < et) || (ei == et && i < t);
    }
    sv[rank] = myv;
    __syncthreads();

    if (t == 0) {
        for (int j = 0; j < KEPT; ++j) counts[sv[j]] += 1.f;
        float Mv = 0.f; int Tc = 0;
        for (int j = 0; j < KEPT; ++j) {
            const int c = sv[j];
            bool dup = false;
            for (int q = 0; q < j; ++q) dup = dup || (sv[q] == c);
            if (dup) continue;
            const float cv = counts[c];
            if (cv > Mv) { Mv = cv; Tc = 1; }
            else if (cv == Mv) { Tc += 1; }
        }
        for (int i = 0; i < NUM_TTA - KEPT; ++i) {
            if (Tc <= 1) break;
            const int c = sv[KEPT + i];
            const float oldc = counts[c];
            counts[c] = oldc + 1.f;
            if (oldc == Mv)            { Mv += 1.f; Tc = 1; }
            else if (oldc + 1.f == Mv) { Tc += 1; }
        }
    }
    __syncthreads();

    const size_t o0 = (size_t)b * N_COLS;
    for (int c = t; c < N_COLS; c += NUM_TTA)
        out[o0 + c] = logf(counts[c] * (1.f / 64.f) + 1e-8f);
}

// -------------------------------- launch --------------------------------
extern "C" void kernel_launch(void* const* d_in, const int* in_sizes, int n_in,
                              void* d_out, int out_size, void* d_ws, size_t ws_size,
                              hipStream_t stream) {
    const float* x    = (const float*)d_in[0];
    const float* Wm   = (const float*)d_in[1];
    const float* bias = (const float*)d_in[2];
    float* out = (float*)d_out;

    // ws layout: ent f64[16384] | votes i32[16384] | Wh,Wl bf16[1024*4096]
    //            | per-chunk: Ah,Al bf16[R*4096], logits f32[R*1000]
    char* p = (char*)d_ws;
    double* ent  = (double*)p;                     p += (size_t)M_ROWS * 8;
    int*   votes = (int*)p;                        p += (size_t)M_ROWS * 4;
    unsigned short* Wh = (unsigned short*)p;       p += (size_t)N_PAD * K_DIM * 2;
    unsigned short* Wl = (unsigned short*)p;       p += (size_t)N_PAD * K_DIM * 2;
    const size_t base = (size_t)(p - (char*)d_ws);

    // R: rows per chunk, multiple of 1024 so m_tiles is divisible by 8
    long long R = 0;
    if (ws_size > base) R = (long long)((ws_size - base) / (size_t)(8192 + 8192 + 4000));
    R = (R / 1024) * 1024;
    if (R > CHUNK_MAX) R = CHUNK_MAX;
    if (R < 1024) R = 1024;

    unsigned short* Ah = (unsigned short*)p;
    unsigned short* Al = Ah + (size_t)R * K_DIM;
    float* logits = (float*)(Al + (size_t)R * K_DIM);

    split_w<<<dim3(K_DIM / 32, N_PAD / 32), dim3(32, 32), 0, stream>>>(Wm, Wh, Wl);

    for (int m0 = 0; m0 < M_ROWS; m0 += (int)R) {
        const int rows = (int)(((long long)(M_ROWS - m0) < R) ? (M_ROWS - m0) : R);
        const int m_tiles = rows / 128;
        const long long nel = (long long)rows * K_DIM;
        split_a<<<(int)((nel / 8 + 255) / 256), 256, 0, stream>>>(
            x + (size_t)m0 * K_DIM, Ah, Al, nel);
        gemm_mfma<<<N_TILES * m_tiles, 256, 0, stream>>>(
            Ah, Al, Wh, Wl, bias, logits, m_tiles);
        row_stats<<<rows / 4, 256, 0, stream>>>(logits, ent, votes, m0);
    }
    vote_kernel<<<BATCH, NUM_TTA, 0, stream>>>(ent, votes, out);
}